// Round 2
// baseline (7517.873 us; speedup 1.0000x reference)
//
#include <hip/hip_runtime.h>

#define NL 50000
#define NS 128
#define G 160
#define GSQ (160*160)
#define GCUBE (160*160*160)

typedef float f32x2 __attribute__((ext_vector_type(2)));

// Packed no-return fp32 atomic pair (global_atomic_pk_add_f32, gfx90a+).
// p must be 8B-aligned. Falls back to two scalar HW atomics.
__device__ __forceinline__ void pk_atomic_add(float* p, float a, float b) {
#if __has_builtin(__builtin_amdgcn_global_atomic_fadd_v2f32)
    typedef __attribute__((address_space(1))) f32x2* gp_t;
    f32x2 v; v.x = a; v.y = b;
    __builtin_amdgcn_global_atomic_fadd_v2f32((gp_t)(unsigned long long)p, v);
#else
    unsafeAtomicAdd(p, a);
    unsafeAtomicAdd(p + 1, b);
#endif
}

// One wave per LOR; each lane handles samples lane and lane+64.
// PA,PB,PC: which pos component maps to stride sa, sb, 1 (unit stride last).
// Gather and scatter share the same flat offsets; bp pairs along the unit
// axis go out as packed atomics when 8B-aligned (unit index even; sa,sb even).
template<int PA, int PB, int PC>
__global__ __launch_bounds__(256) void ray_kernel(
    const float* __restrict__ img,
    const float* __restrict__ lors,   // [6][NL] row-major
    float* __restrict__ bp,
    int sa, int sb)
{
    const int wave = threadIdx.x >> 6;
    const int lane = threadIdx.x & 63;
    const int lor  = blockIdx.x * 4 + wave;

    const float p1x = lors[0*NL + lor];
    const float p1y = lors[1*NL + lor];
    const float p1z = lors[2*NL + lor];
    const float dxv = lors[3*NL + lor] - p1x;
    const float dyv = lors[4*NL + lor] - p1y;
    const float dzv = lors[5*NL + lor] - p1z;
    const float len  = sqrtf(dxv*dxv + dyv*dyv + dzv*dzv);
    const float step = len * (1.0f/NS);

    int   base_[2], ic_[2];
    float wa_[2], wb_[2], wc_[2];
    float sum = 0.0f;

    #pragma unroll
    for (int q = 0; q < 2; ++q) {
        const int s = lane + q*64;
        const float t = ((float)s + 0.5f) * (1.0f/NS);
        const float pos[3] = { p1x + t*dxv, p1y + t*dyv, p1z + t*dzv };

        int ia, ib, ic; float wa, wb, wc;
        {
            float f = (pos[PA] + 100.0f) / 1.25f - 0.5f;
            f = fminf(fmaxf(f, 0.0f), 159.0f);
            ia = (int)f; ia = ia > 158 ? 158 : ia; wa = f - (float)ia;
        }
        {
            float f = (pos[PB] + 100.0f) / 1.25f - 0.5f;
            f = fminf(fmaxf(f, 0.0f), 159.0f);
            ib = (int)f; ib = ib > 158 ? 158 : ib; wb = f - (float)ib;
        }
        {
            float f = (pos[PC] + 100.0f) / 1.25f - 0.5f;
            f = fminf(fmaxf(f, 0.0f), 159.0f);
            ic = (int)f; ic = ic > 158 ? 158 : ic; wc = f - (float)ic;
        }

        const int base = ia*sa + ib*sb + ic;
        const float* g = img + base;
        const float v000 = g[0],       v001 = g[1];
        const float v010 = g[sb],      v011 = g[sb + 1];
        const float v100 = g[sa],      v101 = g[sa + 1];
        const float v110 = g[sa + sb], v111 = g[sa + sb + 1];
        const float c00 = v000 + wc*(v001 - v000);
        const float c01 = v010 + wc*(v011 - v010);
        const float c10 = v100 + wc*(v101 - v100);
        const float c11 = v110 + wc*(v111 - v110);
        const float c0  = c00 + wb*(c01 - c00);
        const float c1  = c10 + wb*(c11 - c10);
        sum += c0 + wa*(c1 - c0);

        base_[q] = base; ic_[q] = ic;
        wa_[q] = wa; wb_[q] = wb; wc_[q] = wc;
    }

    // 64-lane butterfly reduction
    #pragma unroll
    for (int off = 32; off > 0; off >>= 1)
        sum += __shfl_xor(sum, off, 64);

    // contrib = KW * (KW * step * sum) * step
    const float contrib = 9.0f * step * step * sum;

    #pragma unroll
    for (int q = 0; q < 2; ++q) {
        const int base = base_[q];
        const float wa = wa_[q], wb = wb_[q], wc = wc_[q];
        const float ua = 1.0f - wa, ub = 1.0f - wb, uc = 1.0f - wc;
        const float w00 = contrib*ua*ub, w01 = contrib*ua*wb;
        const float w10 = contrib*wa*ub, w11 = contrib*wa*wb;
        float* p00 = bp + base;
        if (!(ic_[q] & 1)) {
            pk_atomic_add(p00,           w00*uc, w00*wc);
            pk_atomic_add(p00 + sb,      w01*uc, w01*wc);
            pk_atomic_add(p00 + sa,      w10*uc, w10*wc);
            pk_atomic_add(p00 + sa + sb, w11*uc, w11*wc);
        } else {
            unsafeAtomicAdd(p00,              w00*uc);
            unsafeAtomicAdd(p00 + 1,          w00*wc);
            unsafeAtomicAdd(p00 + sb,         w01*uc);
            unsafeAtomicAdd(p00 + sb + 1,     w01*wc);
            unsafeAtomicAdd(p00 + sa,         w10*uc);
            unsafeAtomicAdd(p00 + sa + 1,     w10*wc);
            unsafeAtomicAdd(p00 + sa + sb,    w11*uc);
            unsafeAtomicAdd(p00 + sa + sb + 1,w11*wc);
        }
    }
}

__global__ __launch_bounds__(256) void finalize_kernel(
    const float4* __restrict__ img, const float4* __restrict__ eff,
    float4* __restrict__ out)
{
    const int i = blockIdx.x * 256 + threadIdx.x;
    const float4 a = img[i];
    const float4 e = eff[i];
    float4 o = out[i];
    o.x *= a.x * e.x;
    o.y *= a.y * e.y;
    o.z *= a.z * e.z;
    o.w *= a.w * e.w;
    out[i] = o;
}

extern "C" void kernel_launch(void* const* d_in, const int* in_sizes, int n_in,
                              void* d_out, int out_size, void* d_ws, size_t ws_size,
                              hipStream_t stream) {
    const float* img = (const float*)d_in[0];
    const float* eff = (const float*)d_in[1];
    const float* xl  = (const float*)d_in[2];
    const float* yl  = (const float*)d_in[3];
    const float* zl  = (const float*)d_in[4];
    float* out = (float*)d_out;

    hipMemsetAsync(out, 0, (size_t)out_size * sizeof(float), stream);

    const dim3 blk(256);
    const dim3 grd(NL / 4);   // 4 waves/block, one LOR per wave
    // z-pass: base = i0*GSQ + i1*G + i2     (unit axis = 2)
    ray_kernel<0,1,2><<<grd, blk, 0, stream>>>(img, zl, out, GSQ, G);
    // x-pass: base = i0*1 + i1*GSQ + i2*G   (unit axis = 0)
    ray_kernel<1,2,0><<<grd, blk, 0, stream>>>(img, xl, out, GSQ, G);
    // y-pass: base = i0*G + i1*GSQ + i2*1   (unit axis = 2)
    ray_kernel<0,1,2><<<grd, blk, 0, stream>>>(img, yl, out, G, GSQ);

    finalize_kernel<<<GCUBE/4/256, 256, 0, stream>>>(
        (const float4*)img, (const float4*)eff, (float4*)out);
}

// Round 3
// 2567.617 us; speedup vs baseline: 2.9280x; 2.9280x over previous
//
#include <hip/hip_runtime.h>

#define NL 50000
#define NS 128
#define G 160
#define GSQ (160*160)
#define GCUBE (160*160*160)

// f -> (base index, frac weight); identical math to reference:
// f = (pos-origin)/vsize - 0.5, clipped; i = clip(floor(f),0,158); w = f-i.
__device__ __forceinline__ void coordf(float pos, int& i, float& w) {
    float f = (pos + 100.0f) * 0.8f - 0.5f;   // origin=-100, vsize=1.25 (1/1.25==0.8 exact)
    f = fminf(fmaxf(f, 0.0f), 159.0f);
    int ii = (int)f; ii = ii > 158 ? 158 : ii;
    i = ii; w = f - (float)ii;
}

__device__ __forceinline__ void lds_add(float* p, float v) {
    __hip_atomic_fetch_add(p, v, __ATOMIC_RELAXED, __HIP_MEMORY_SCOPE_WORKGROUP);
}

// ---------------- Stage 1: projection (pure gather) ----------------
// One wave per LOR, lanes = samples (2/lane). Writes contrib[lor] =
// KW * (KW*step*sum) * step = 9*step^2*sum. No scatter.
template<int PA, int PB, int PC>
__global__ __launch_bounds__(256) void proj_kernel(
    const float* __restrict__ img,
    const float* __restrict__ lors,   // [6][NL]
    float* __restrict__ contrib,
    int sa, int sb)
{
    const int wave = threadIdx.x >> 6;
    const int lane = threadIdx.x & 63;
    const int lor  = blockIdx.x * 4 + wave;

    const float p1x = lors[0*NL + lor];
    const float p1y = lors[1*NL + lor];
    const float p1z = lors[2*NL + lor];
    const float dxv = lors[3*NL + lor] - p1x;
    const float dyv = lors[4*NL + lor] - p1y;
    const float dzv = lors[5*NL + lor] - p1z;
    const float len  = sqrtf(dxv*dxv + dyv*dyv + dzv*dzv);
    const float step = len * (1.0f/NS);

    float sum = 0.0f;
    #pragma unroll
    for (int q = 0; q < 2; ++q) {
        const int s = lane + q*64;
        const float t = ((float)s + 0.5f) * (1.0f/NS);
        const float pos[3] = { p1x + t*dxv, p1y + t*dyv, p1z + t*dzv };
        int ia, ib, ic; float wa, wb, wc;
        coordf(pos[PA], ia, wa);
        coordf(pos[PB], ib, wb);
        coordf(pos[PC], ic, wc);
        const float* g = img + ia*sa + ib*sb + ic;
        const float v000 = g[0],       v001 = g[1];
        const float v010 = g[sb],      v011 = g[sb + 1];
        const float v100 = g[sa],      v101 = g[sa + 1];
        const float v110 = g[sa + sb], v111 = g[sa + sb + 1];
        const float c00 = v000 + wc*(v001 - v000);
        const float c01 = v010 + wc*(v011 - v010);
        const float c10 = v100 + wc*(v101 - v100);
        const float c11 = v110 + wc*(v111 - v110);
        const float c0  = c00 + wb*(c01 - c00);
        const float c1  = c10 + wb*(c11 - c10);
        sum += c0 + wa*(c1 - c0);
    }

    #pragma unroll
    for (int off = 32; off > 0; off >>= 1)
        sum += __shfl_xor(sum, off, 64);

    if (lane == 0)
        contrib[lor] = 9.0f * step * step * sum;
}

// ---------------- Stage 2: slab backprojection (LDS-privatized) ----------------
// Workgroup owns output plane p (the stride-GSQ axis). A sample at base
// (ia,ib,ic) adds to planes ia (weight 1-wa) and ia+1 (weight wa). For each
// ray, the samples with ia in {p-1,p} form a contiguous t-range (f linear in
// t); we solve it conservatively and recheck each candidate exactly.
// PS/PR/PC2: pos components of the slab (GSQ), row (G), col (1) axes.
template<int PS, int PR, int PC2>
__device__ __forceinline__ void slab_accum(
    float* __restrict__ plane,
    const float* __restrict__ lors,
    const float* __restrict__ contrib,
    int p, int tid, int nthreads)
{
    const float glo = (p - 1 <= 0)   ? -1e30f : (float)(p - 1);
    const float ghi = (p + 1 >= 159) ?  1e30f : (float)(p + 1);

    for (int r = tid; r < NL; r += nthreads) {
        const float q0 = lors[0*NL + r], q1 = lors[1*NL + r], q2 = lors[2*NL + r];
        const float d0 = lors[3*NL + r] - q0;
        const float d1 = lors[4*NL + r] - q1;
        const float d2 = lors[5*NL + r] - q2;
        const float p1[3] = { q0, q1, q2 };
        const float dv[3] = { d0, d1, d2 };
        const float cb = contrib[r];

        const float A = (p1[PS] + 100.0f) * 0.8f - 0.5f;
        const float B = dv[PS] * 0.8f;

        int slo, shi;
        if (fabsf(B) < 1e-12f) {
            if (A < glo || A > ghi) continue;
            slo = 0; shi = NS - 1;
        } else {
            const float t1 = (glo - A) / B, t2 = (ghi - A) / B;
            const float tlo = fminf(t1, t2), thi = fmaxf(t1, t2);
            slo = (int)fmaxf(0.0f, floorf(tlo * (float)NS - 0.5f) - 1.0f);
            shi = (int)fminf((float)(NS - 1), ceilf(thi * (float)NS - 0.5f) + 1.0f);
            if (slo > shi) continue;
        }

        for (int s = slo; s <= shi; ++s) {
            const float t = ((float)s + 0.5f) * (1.0f/NS);
            int ia; float wa; coordf(p1[PS] + t*dv[PS], ia, wa);
            float fa;
            if (ia == p)          fa = 1.0f - wa;
            else if (ia == p - 1) fa = wa;
            else continue;
            int ib; float wb; coordf(p1[PR]  + t*dv[PR],  ib, wb);
            int ic; float wc; coordf(p1[PC2] + t*dv[PC2], ic, wc);
            const float v  = fa * cb;
            const float v0 = v * (1.0f - wb), v1 = v * wb;
            float* q = plane + ib * G + ic;
            lds_add(q,         v0 * (1.0f - wc));
            lds_add(q + 1,     v0 * wc);
            lds_add(q + G,     v1 * (1.0f - wc));
            lds_add(q + G + 1, v1 * wc);
        }
    }
}

__global__ __launch_bounds__(512) void bp_kernel(
    const float* __restrict__ img, const float* __restrict__ eff,
    const float* __restrict__ zl, const float* __restrict__ xl,
    const float* __restrict__ yl,
    const float* __restrict__ cz, const float* __restrict__ cx,
    const float* __restrict__ cy,
    float* __restrict__ out)
{
    __shared__ float plane[GSQ];
    const int p   = blockIdx.x;
    const int tid = threadIdx.x;

    for (int j = tid; j < GSQ; j += 512) plane[j] = 0.0f;
    __syncthreads();

    // z-pass: base = i0*GSQ + i1*G + i2   -> slab=pos0, row=pos1, col=pos2
    slab_accum<0,1,2>(plane, zl, cz, p, tid, 512);
    // x-pass: base = i1*GSQ + i2*G + i0   -> slab=pos1, row=pos2, col=pos0
    slab_accum<1,2,0>(plane, xl, cx, p, tid, 512);
    // y-pass: base = i1*GSQ + i0*G + i2   -> slab=pos1, row=pos0, col=pos2
    slab_accum<1,0,2>(plane, yl, cy, p, tid, 512);

    __syncthreads();

    // Fused finalize: out = plane * img * eff on this WG's disjoint plane.
    const int base = p * GSQ;
    for (int j = tid; j < GSQ; j += 512) {
        const int idx = base + j;
        out[idx] = plane[j] * img[idx] * eff[idx];
    }
}

extern "C" void kernel_launch(void* const* d_in, const int* in_sizes, int n_in,
                              void* d_out, int out_size, void* d_ws, size_t ws_size,
                              hipStream_t stream) {
    const float* img = (const float*)d_in[0];
    const float* eff = (const float*)d_in[1];
    const float* xl  = (const float*)d_in[2];
    const float* yl  = (const float*)d_in[3];
    const float* zl  = (const float*)d_in[4];
    float* out = (float*)d_out;

    float* cz = (float*)d_ws;
    float* cx = cz + NL;
    float* cy = cx + NL;

    const dim3 blk(256);
    const dim3 grd(NL / 4);   // 4 waves/block, one LOR per wave
    // z-pass: base = i0*GSQ + i1*G + i2
    proj_kernel<0,1,2><<<grd, blk, 0, stream>>>(img, zl, cz, GSQ, G);
    // x-pass: base = i1*GSQ + i2*G + i0
    proj_kernel<1,2,0><<<grd, blk, 0, stream>>>(img, xl, cx, GSQ, G);
    // y-pass: base = i0*G + i1*GSQ + i2
    proj_kernel<0,1,2><<<grd, blk, 0, stream>>>(img, yl, cy, G, GSQ);

    bp_kernel<<<dim3(G), dim3(512), 0, stream>>>(img, eff, zl, xl, yl, cz, cx, cy, out);
}